// Round 4
// baseline (194.491 us; speedup 1.0000x reference)
//
#include <hip/hip_runtime.h>

// CovarianceLayer: x [B=64, C=4, T=8192, M=16] fp32 -> cov [B, C, 16, 16] fp32
// cov = (P - S S^T / T) / (T-1),  P = X^T X.
//
// R13 = R12 resubmitted verbatim (GPU-acquisition timeout; R12 never ran --
// not stacking untested changes on an unmeasured structural rewrite).
//
// R12: drop MFMA+LDS entirely -> pure-VALU fp32 outer product with DPP
// quad-perm gathers.
//
// Evidence: R10's contiguous-NT fix was neutral (181.4 -> 177.8us), killing
// the read-amplification theory. rocprof top-5 shows only the harness's
// 537MB poison fills (~80us @ 6.9TB/s); cov_kernel < 78us -> the harness
// metric carries ~100us of fixed fill+overhead and the kernel sits at
// ~55-78us vs a 21us HBM floor (134MB @ 6.3TB/s). Six read-path experiments
// (vectorization, PF depth, decomposition, CU count, NT vs cached,
// coalescing) all neutral -> the pin is downstream: the per-round serial
// chain vmcnt -> pack(~30 VALU) -> ds_write -> lgkmcnt(0) -> ds_read_b128
// -> MFMA, paid per 2KB per wave, intra-wave serial.
//
// R12 structure: 4 consecutive lanes share one 64B row; lane loads its 16B
// quarter (per-instruction: 64 lanes cover 16 rows = 1KB contiguous, every
// byte fetched exactly once). Three mov_dpp quad_perms (xor 1,2,3) gather
// the other quarters in-register on the VALU pipe -- no LDS, no barriers,
// no bf16 pack, no MFMA in the main loop. Lane accumulates
// acc[i][d][j] = P[4qt+i][4(qt^d)+j] (64 fp32 FMA per 16B): over qt and d
// this covers all 256 (m,n) pairs exactly once per row.
// Arithmetic: 537M FMA chip-wide = 6.8us at 78.6T FMA/s vector peak, under
// the 21us HBM floor with 3.1x margin; per-SIMD issue ~61 GB/s/CU vs the
// 25 GB/s/CU HBM share. Prediction: kernel -> ~22-30us if the consumer
// pipeline was the binder; neutral if the read stream itself pins.
//
// Epilogue: 4-step shfl_xor butterfly over the 16 row-slot lanes per
// quarter, 8KB LDS combine across waves, fp32 finalize (absmax ~1e-6 vs
// bf16's 7.8e-3).

constexpr int T_DIM  = 8192;
constexpr int M_DIM  = 16;
constexpr int BLOCK  = 512;                        // 8 waves, 1 block/(b,c)
constexpr int NWAVE  = BLOCK / 64;                 // 8
constexpr int ROUNDS = T_DIM * M_DIM / 4 / BLOCK;  // 64 f32x4 rounds/thread
constexpr int PF     = 4;                          // prefetch depth (rounds)

using f32x4 = __attribute__((ext_vector_type(4))) float;

// quad_perm DPP move: result(lane) = x(lane ^ k) within each 4-lane group.
// ctrl byte = perm[0] | perm[1]<<2 | perm[2]<<4 | perm[3]<<6.
template <int CTRL>
static __device__ inline float qperm(float x) {
    int xi = __builtin_bit_cast(int, x);
    int r  = __builtin_amdgcn_update_dpp(xi, xi, CTRL, 0xF, 0xF, true);
    return __builtin_bit_cast(float, r);
}
constexpr int DPP_XOR1 = 0xB1;  // [1,0,3,2]
constexpr int DPP_XOR2 = 0x4E;  // [2,3,0,1]
constexpr int DPP_XOR3 = 0x1B;  // [3,2,1,0]

__global__ __launch_bounds__(BLOCK, 2)
void cov_kernel(const float* __restrict__ x, float* __restrict__ out) {
    const int bc   = blockIdx.x;
    const int tid  = threadIdx.x;
    const int wave = tid >> 6;
    const int lane = tid & 63;
    const int qt   = lane & 3;      // column-quarter owned by this lane

    __shared__ float Pred[NWAVE * 4 * 64];   // [wave][qt][i*16+d*4+j], 8KB
    __shared__ float Sred[NWAVE * 4 * 4];    // [wave][qt][i]
    __shared__ float Stot[M_DIM];

    const f32x4* __restrict__ xin =
        (const f32x4*)(x + (size_t)bc * (T_DIM * M_DIM));

    // acc[i][d][j] accumulates x[row][4qt+i] * x[row][4(qt^d)+j]
    float acc[4][4][4];
#pragma unroll
    for (int i = 0; i < 4; ++i)
#pragma unroll
        for (int d = 0; d < 4; ++d)
#pragma unroll
            for (int j = 0; j < 4; ++j) acc[i][d][j] = 0.f;
    float s[4] = {0.f, 0.f, 0.f, 0.f};

    auto do_round = [&](const f32x4 v) {
        float c1[4], c2[4], c3[4];
#pragma unroll
        for (int j = 0; j < 4; ++j) {
            c1[j] = qperm<DPP_XOR1>(v[j]);   // cols of quarter qt^1
            c2[j] = qperm<DPP_XOR2>(v[j]);   // qt^2
            c3[j] = qperm<DPP_XOR3>(v[j]);   // qt^3
        }
#pragma unroll
        for (int i = 0; i < 4; ++i) {
            s[i] += v[i];
#pragma unroll
            for (int j = 0; j < 4; ++j) {
                acc[i][0][j] = fmaf(v[i], v[j],  acc[i][0][j]);
                acc[i][1][j] = fmaf(v[i], c1[j], acc[i][1][j]);
                acc[i][2][j] = fmaf(v[i], c2[j], acc[i][2][j]);
                acc[i][3][j] = fmaf(v[i], c3[j], acc[i][3][j]);
            }
        }
    };

    // Round r: block reads f4[r*512 + tid] -- one contiguous 8KB slab.
    f32x4 buf[PF];
#pragma unroll
    for (int r = 0; r < PF; ++r) buf[r] = xin[(size_t)r * BLOCK + tid];

    for (int it = 0; it < ROUNDS / PF - 1; ++it) {
#pragma unroll
        for (int u = 0; u < PF; ++u) {
            const f32x4 v = buf[u];
            buf[u] = xin[(size_t)((it + 1) * PF + u) * BLOCK + tid];
            do_round(v);
        }
    }
#pragma unroll
    for (int u = 0; u < PF; ++u) do_round(buf[u]);   // tail, no loads

    // Butterfly over the 16 row-slot lanes sharing this qt (lane bits 2..5),
    // then lanes 0..3 (qt==lane) publish wave partials.
#pragma unroll
    for (int i = 0; i < 4; ++i)
#pragma unroll
        for (int d = 0; d < 4; ++d)
#pragma unroll
            for (int j = 0; j < 4; ++j) {
                float a = acc[i][d][j];
                a += __shfl_xor(a, 4, 64);
                a += __shfl_xor(a, 8, 64);
                a += __shfl_xor(a, 16, 64);
                a += __shfl_xor(a, 32, 64);
                acc[i][d][j] = a;
            }
#pragma unroll
    for (int i = 0; i < 4; ++i) {
        float a = s[i];
        a += __shfl_xor(a, 4, 64);
        a += __shfl_xor(a, 8, 64);
        a += __shfl_xor(a, 16, 64);
        a += __shfl_xor(a, 32, 64);
        s[i] = a;
    }
    if (lane < 4) {
#pragma unroll
        for (int i = 0; i < 4; ++i) {
#pragma unroll
            for (int d = 0; d < 4; ++d)
#pragma unroll
                for (int j = 0; j < 4; ++j)
                    Pred[(wave * 4 + qt) * 64 + (i * 16 + d * 4 + j)] =
                        acc[i][d][j];
            Sred[(wave * 4 + qt) * 4 + i] = s[i];
        }
    }
    __syncthreads();

    if (tid < M_DIM) {
        const int a_ = tid >> 2, i = tid & 3;
        float ssum = 0.f;
#pragma unroll
        for (int w = 0; w < NWAVE; ++w) ssum += Sred[(w * 4 + a_) * 4 + i];
        Stot[tid] = ssum;
    }
    __syncthreads();

    if (tid < 256) {
        const int m = tid >> 4, n = tid & 15;
        const int a_ = m >> 2, i = m & 3;
        const int b_ = n >> 2, j = n & 3;
        const int d  = a_ ^ b_;
        const int p  = i * 16 + d * 4 + j;
        float P = 0.f;
#pragma unroll
        for (int w = 0; w < NWAVE; ++w) P += Pred[(w * 4 + a_) * 64 + p];
        const float cov =
            (P - Stot[m] * Stot[n] * (1.0f / (float)T_DIM)) *
            (1.0f / (float)(T_DIM - 1));
        out[(size_t)bc * 256 + tid] = cov;
    }
}

extern "C" void kernel_launch(void* const* d_in, const int* in_sizes, int n_in,
                              void* d_out, int out_size, void* d_ws, size_t ws_size,
                              hipStream_t stream) {
    const float* x = (const float*)d_in[0];
    float* out = (float*)d_out;
    const int n_bc = in_sizes[0] / (T_DIM * M_DIM);   // B*C = 256
    cov_kernel<<<dim3(n_bc), dim3(BLOCK), 0, stream>>>(x, out);
}

// Round 5
// 191.910 us; speedup vs baseline: 1.0135x; 1.0135x over previous
//
#include <hip/hip_runtime.h>

// CovarianceLayer: x [B=64, C=4, T=8192, M=16] fp32 -> cov [B, C, 16, 16] fp32
// cov = (P - S S^T / T) / (T-1),  P = X^T X.
//
// R14 = R12 + per-block ROUND-ORDER ROTATION (one-variable change vs the
// measured R12 = 194.5us).
//
// Evidence trail: R10 (MFMA+LDS, BLOCK=1024) = 177.8us; R12 (pure VALU+DPP,
// BLOCK=512) = 194.5us. Two radically different consumers within 10% ->
// the consumer is NOT the binder. Combined with R7 (half CUs -> +10% only),
// the pin is CHIP-LEVEL, invariant to: vectorization, PF depth,
// decomposition, CU count, NT vs cached, coalescing, consumer structure.
//
// Remaining theory: DRAM channel/bank imbalance from power-of-2 stream
// pitch. Every variant so far runs N concurrent read streams at a
// power-of-2 pitch (R12: 256 streams at 512KB pitch -- at any instant the
// chip reads 256 slabs spaced exactly 512KB apart). If the HBM channel
// interleave is linear, that pitch aliases onto a channel subset -> all
// streams hammer the same channels -> ~2.5TB/s read pin. The harness fill
// (single dense front) does 6.9TB/s on the same part.
//
// Fix under test: block bc visits its 64 slabs in rotated order
// (r + bc*37) & 63. Accumulation is order-invariant; the instantaneous
// chip-wide footprint decorrelates across channels. Inner loop unchanged
// (slab index is block-uniform -> SGPR).
//
// Pre-committed read: dur_us <=170 confirms (<=155 strong); 194.5 +/- 8
// kills the theory -> next lever is occupancy on the R10 base.
//
// Structure (unchanged from R12): 4 consecutive lanes share one 64B row;
// lane loads its 16B quarter; 3 mov_dpp quad_perms gather the other
// quarters in-register; acc[i][d][j] = P[4qt+i][4(qt^d)+j] covers all 256
// (m,n) once per row. No LDS/barriers/MFMA in main loop. Epilogue:
// shfl_xor butterfly + 8KB LDS combine + fp32 finalize.

constexpr int T_DIM  = 8192;
constexpr int M_DIM  = 16;
constexpr int BLOCK  = 512;                        // 8 waves, 1 block/(b,c)
constexpr int NWAVE  = BLOCK / 64;                 // 8
constexpr int ROUNDS = T_DIM * M_DIM / 4 / BLOCK;  // 64 f32x4 rounds/thread
constexpr int PF     = 4;                          // prefetch depth (rounds)

using f32x4 = __attribute__((ext_vector_type(4))) float;

// quad_perm DPP move: result(lane) = x(lane ^ k) within each 4-lane group.
template <int CTRL>
static __device__ inline float qperm(float x) {
    int xi = __builtin_bit_cast(int, x);
    int r  = __builtin_amdgcn_update_dpp(xi, xi, CTRL, 0xF, 0xF, true);
    return __builtin_bit_cast(float, r);
}
constexpr int DPP_XOR1 = 0xB1;  // [1,0,3,2]
constexpr int DPP_XOR2 = 0x4E;  // [2,3,0,1]
constexpr int DPP_XOR3 = 0x1B;  // [3,2,1,0]

__global__ __launch_bounds__(BLOCK, 2)
void cov_kernel(const float* __restrict__ x, float* __restrict__ out) {
    const int bc   = blockIdx.x;
    const int tid  = threadIdx.x;
    const int wave = tid >> 6;
    const int lane = tid & 63;
    const int qt   = lane & 3;      // column-quarter owned by this lane

    // Per-block rotation of the slab visit order (order-invariant sum).
    const int rot = (bc * 37) & (ROUNDS - 1);

    __shared__ float Pred[NWAVE * 4 * 64];   // [wave][qt][i*16+d*4+j], 8KB
    __shared__ float Sred[NWAVE * 4 * 4];    // [wave][qt][i]
    __shared__ float Stot[M_DIM];

    const f32x4* __restrict__ xin =
        (const f32x4*)(x + (size_t)bc * (T_DIM * M_DIM));

    // acc[i][d][j] accumulates x[row][4qt+i] * x[row][4(qt^d)+j]
    float acc[4][4][4];
#pragma unroll
    for (int i = 0; i < 4; ++i)
#pragma unroll
        for (int d = 0; d < 4; ++d)
#pragma unroll
            for (int j = 0; j < 4; ++j) acc[i][d][j] = 0.f;
    float s[4] = {0.f, 0.f, 0.f, 0.f};

    auto do_round = [&](const f32x4 v) {
        float c1[4], c2[4], c3[4];
#pragma unroll
        for (int j = 0; j < 4; ++j) {
            c1[j] = qperm<DPP_XOR1>(v[j]);   // cols of quarter qt^1
            c2[j] = qperm<DPP_XOR2>(v[j]);   // qt^2
            c3[j] = qperm<DPP_XOR3>(v[j]);   // qt^3
        }
#pragma unroll
        for (int i = 0; i < 4; ++i) {
            s[i] += v[i];
#pragma unroll
            for (int j = 0; j < 4; ++j) {
                acc[i][0][j] = fmaf(v[i], v[j],  acc[i][0][j]);
                acc[i][1][j] = fmaf(v[i], c1[j], acc[i][1][j]);
                acc[i][2][j] = fmaf(v[i], c2[j], acc[i][2][j]);
                acc[i][3][j] = fmaf(v[i], c3[j], acc[i][3][j]);
            }
        }
    };

    // Logical round lr reads physical slab ((lr + rot) & 63); a slab is one
    // contiguous 8KB block read: f4[slab*512 + tid].
    auto slab_addr = [&](int lr) -> const f32x4* {
        const int sp = (lr + rot) & (ROUNDS - 1);
        return &xin[(size_t)sp * BLOCK + tid];
    };

    f32x4 buf[PF];
#pragma unroll
    for (int r = 0; r < PF; ++r) buf[r] = *slab_addr(r);

    for (int it = 0; it < ROUNDS / PF - 1; ++it) {
#pragma unroll
        for (int u = 0; u < PF; ++u) {
            const f32x4 v = buf[u];
            buf[u] = *slab_addr((it + 1) * PF + u);
            do_round(v);
        }
    }
#pragma unroll
    for (int u = 0; u < PF; ++u) do_round(buf[u]);   // tail, no loads

    // Butterfly over the 16 row-slot lanes sharing this qt (lane bits 2..5),
    // then lanes 0..3 (qt==lane) publish wave partials.
#pragma unroll
    for (int i = 0; i < 4; ++i)
#pragma unroll
        for (int d = 0; d < 4; ++d)
#pragma unroll
            for (int j = 0; j < 4; ++j) {
                float a = acc[i][d][j];
                a += __shfl_xor(a, 4, 64);
                a += __shfl_xor(a, 8, 64);
                a += __shfl_xor(a, 16, 64);
                a += __shfl_xor(a, 32, 64);
                acc[i][d][j] = a;
            }
#pragma unroll
    for (int i = 0; i < 4; ++i) {
        float a = s[i];
        a += __shfl_xor(a, 4, 64);
        a += __shfl_xor(a, 8, 64);
        a += __shfl_xor(a, 16, 64);
        a += __shfl_xor(a, 32, 64);
        s[i] = a;
    }
    if (lane < 4) {
#pragma unroll
        for (int i = 0; i < 4; ++i) {
#pragma unroll
            for (int d = 0; d < 4; ++d)
#pragma unroll
                for (int j = 0; j < 4; ++j)
                    Pred[(wave * 4 + qt) * 64 + (i * 16 + d * 4 + j)] =
                        acc[i][d][j];
            Sred[(wave * 4 + qt) * 4 + i] = s[i];
        }
    }
    __syncthreads();

    if (tid < M_DIM) {
        const int a_ = tid >> 2, i = tid & 3;
        float ssum = 0.f;
#pragma unroll
        for (int w = 0; w < NWAVE; ++w) ssum += Sred[(w * 4 + a_) * 4 + i];
        Stot[tid] = ssum;
    }
    __syncthreads();

    if (tid < 256) {
        const int m = tid >> 4, n = tid & 15;
        const int a_ = m >> 2, i = m & 3;
        const int b_ = n >> 2, j = n & 3;
        const int d  = a_ ^ b_;
        const int p  = i * 16 + d * 4 + j;
        float P = 0.f;
#pragma unroll
        for (int w = 0; w < NWAVE; ++w) P += Pred[(w * 4 + a_) * 64 + p];
        const float cov =
            (P - Stot[m] * Stot[n] * (1.0f / (float)T_DIM)) *
            (1.0f / (float)(T_DIM - 1));
        out[(size_t)bc * 256 + tid] = cov;
    }
}

extern "C" void kernel_launch(void* const* d_in, const int* in_sizes, int n_in,
                              void* d_out, int out_size, void* d_ws, size_t ws_size,
                              hipStream_t stream) {
    const float* x = (const float*)d_in[0];
    float* out = (float*)d_out;
    const int n_bc = in_sizes[0] / (T_DIM * M_DIM);   // B*C = 256
    cov_kernel<<<dim3(n_bc), dim3(BLOCK), 0, stream>>>(x, out);
}